// Round 2
// baseline (739.658 us; speedup 1.0000x reference)
//
#include <hip/hip_runtime.h>
#include <hip/hip_cooperative_groups.h>
#include <stdint.h>
#include <math.h>

namespace cg = cooperative_groups;

#define B_    64
#define C_    256
#define HW_   4096
#define E_    4
#define OUT_  65
#define NPAD_ 80

#define LOGITS_SZ (B_*OUT_*HW_)   /* 17,039,360 */
#define PROB_SZ   (B_*512*512)    /* 16,777,216 */

/* ws byte offsets */
#define POOLED_OFF 0u         /* 64*256 f32 = 65536 */
#define IDX_OFF    65536u     /* 64 i32 = 256 */
#define BNS_OFF    65792u     /* 8 spread copies x 80 f32 = 2560 */
#define BNSS_OFF   68352u     /* 8 x 80 f32 = 2560 */
#define CLEAR_BYTES 70912u
#define WT_OFF     70912u     /* 4*5*8*64*8 bf16 = 163840 */
#define YB_OFF     234752u    /* fallback only: 64*65*4096 bf16 = 34,078,720 */

typedef float  f4 __attribute__((ext_vector_type(4)));
typedef short  s8 __attribute__((ext_vector_type(8)));

__device__ __forceinline__ uint32_t f2bf(float f){
  uint32_t u = __float_as_uint(f);
  return (u + 0x7FFFu + ((u >> 16) & 1u)) >> 16;
}
__device__ __forceinline__ uint32_t pk(float lo, float hi){
  return f2bf(lo) | (f2bf(hi) << 16);
}
__device__ __forceinline__ float bf2f(uint32_t u){
  return __uint_as_float((u & 0xFFFFu) << 16);
}

/* xb tiled layout (MFMA A-fragment order):
   elem(p, c) -> [b][T=p>>4][ks=c>>5][lane=(p&15)*4 + ((c>>3)&3)][j=c&7] */

/* ---------------- K1: relu + pool(sum) + transpose-to-bf16 + Wt pack ------ */
__global__ __launch_bounds__(256) void k_prep(const float* __restrict__ x,
                                              const float* __restrict__ w_experts,
                                              uint16_t* __restrict__ xb,
                                              uint16_t* __restrict__ Wt,
                                              float* __restrict__ pooled){
  __shared__ float pool_lds[64];
  int bid = blockIdx.x;
  int t = threadIdx.x;

  if (bid >= 8192){
    if (t >= 32) return;
    int pid = bid - 8192;
    int e = pid / NPAD_, o = pid % NPAD_;
    int ks = t >> 2, quad = t & 3;
    int c = t*8;
    float a[8];
    if (o < OUT_){
      const float* src = w_experts + (size_t)e*C_*OUT_ + o;
#pragma unroll
      for (int j = 0; j < 8; ++j) a[j] = src[(size_t)(c+j)*OUT_];
    } else {
#pragma unroll
      for (int j = 0; j < 8; ++j) a[j] = 0.f;
    }
    uint4 wv;
    wv.x = pk(a[0],a[1]); wv.y = pk(a[2],a[3]);
    wv.z = pk(a[4],a[5]); wv.w = pk(a[6],a[7]);
    uint16_t* dst = Wt + ((((size_t)(e*5 + (o>>4))*8 + ks)*64)
                          + (size_t)((o&15)*4 + quad))*8;
    *(uint4*)dst = wv;
    return;
  }

  int b = bid >> 7, ct = (bid >> 5) & 3, pt = bid & 31;
  int cg_ = t & 7, pgg = t >> 3;
  int c0 = ct*64 + cg_*8;
  int p0 = pt*128 + pgg*4;
  if (t < 64) pool_lds[t] = 0.f;
  __syncthreads();

  float v[8][4]; float s[8];
  const float* xp = x + ((size_t)(b*C_ + c0))*HW_ + p0;
#pragma unroll
  for (int r = 0; r < 8; ++r){
    float4 f = *(const float4*)(xp + (size_t)r*HW_);
    v[r][0]=fmaxf(f.x,0.f); v[r][1]=fmaxf(f.y,0.f);
    v[r][2]=fmaxf(f.z,0.f); v[r][3]=fmaxf(f.w,0.f);
    s[r] = v[r][0]+v[r][1]+v[r][2]+v[r][3];
  }
  int ksg  = ct*2 + (cg_ >> 2);
  int quad = cg_ & 3;
#pragma unroll
  for (int pp = 0; pp < 4; ++pp){
    int p = p0 + pp;
    uint16_t* dst = xb + ((((size_t)(b*256 + (p>>4))*8 + ksg)*64)
                          + (size_t)((p&15)*4 + quad))*8;
    uint4 w;
    w.x = pk(v[0][pp], v[1][pp]); w.y = pk(v[2][pp], v[3][pp]);
    w.z = pk(v[4][pp], v[5][pp]); w.w = pk(v[6][pp], v[7][pp]);
    *(uint4*)dst = w;
  }
#pragma unroll
  for (int r = 0; r < 8; ++r){
    float vv = s[r];
    vv += __shfl_xor(vv, 8);
    vv += __shfl_xor(vv, 16);
    vv += __shfl_xor(vv, 32);
    if ((t & 56) == 0)
      atomicAdd(&pool_lds[cg_*8 + r], vv);
  }
  __syncthreads();
  if (t < 64) atomicAdd(pooled + b*C_ + ct*64 + t, pool_lds[t]);
}

/* ---------------- K2: gate + argmax + lb (deterministic, 1 block) --------- */
__global__ void k_lb(const float* __restrict__ pooled_sum,
                     const float* __restrict__ w_gate,
                     const float* __restrict__ b_gate,
                     int* __restrict__ idx_ws,
                     float* __restrict__ out_lb){
  __shared__ float gl[64][4];
  __shared__ int ish[64];
  int t = threadIdx.x;
  int b = t >> 2, e = t & 3;
  float dot = 0.f;
  const float* pr = pooled_sum + b*C_;
  for (int c = 0; c < C_; c += 4){
    float4 p4 = *(const float4*)(pr + c);
    dot += p4.x*w_gate[c*4+e] + p4.y*w_gate[(c+1)*4+e]
         + p4.z*w_gate[(c+2)*4+e] + p4.w*w_gate[(c+3)*4+e];
  }
  gl[b][e] = dot * (1.f/4096.f) + b_gate[e];
  __syncthreads();
  if (t < 64){
    float best = gl[t][0]; int bi = 0;
    for (int ee = 1; ee < 4; ++ee){ float vv = gl[t][ee]; if (vv > best){best = vv; bi = ee;} }
    idx_ws[t] = bi; ish[t] = bi;
  }
  __syncthreads();
  if (t == 0){
    int cnt[4] = {0,0,0,0};
    for (int bb = 0; bb < 64; ++bb) cnt[ish[bb]]++;
    double u[4], S = 0.0;
    for (int ee = 0; ee < 4; ++ee){ u[ee] = cnt[ee]/64.0 + 1e-6; S += u[ee]; }
    double lb = 0.0;
    for (int ee = 0; ee < 4; ++ee){ double uu = u[ee]/S; lb += uu*(log(uu) - log(0.25)); }
    *out_lb = (float)lb;
  }
}

/* ---------------- K3 (coop): GEMM+BN || grid.sync || BN+softmax+shuffle --- */
/* grid 1024 = 64b * 16pt(256px); block 256 = 4 waves; LDS 18.2KB; VGPR<=128
   -> runtime occupancy 4 blocks/CU (LDS would allow 8) = exactly 1024. */
__global__ __launch_bounds__(256, 4) void k_fused(
    const uint16_t* __restrict__ xb, const uint16_t* __restrict__ Wt,
    const int* __restrict__ idx_ws, const float* __restrict__ b_experts,
    const float* __restrict__ gamma, const float* __restrict__ beta,
    float* __restrict__ bnsum, float* __restrict__ bnss,
    float* __restrict__ out_logits, float* __restrict__ out_prob){
  __shared__ union ShMem {
    float2 bnp[NPAD_*4];                                   /* 2560 B */
    struct { uint16_t lt[OUT_*136]; float2 ss[OUT_]; } fin; /* 17680+520 B */
  } sh;

  int bid = blockIdx.x;
  int b = bid >> 4, pt = bid & 15;
  int t = threadIdx.x;
  int w = t >> 6, lane = t & 63;
  int l15 = lane & 15, quad = lane >> 4;
  int lid = l15*4 + quad;
  int e = idx_ws[b];

  /* ---- Phase B: GEMM, acc stays in registers ---- */
  int p0 = pt*256 + w*64;
  const uint16_t* ap = xb + ((size_t)(b*256 + pt*16 + w*4))*4096 + (size_t)lid*8;
  const uint16_t* bp = Wt + (size_t)e*5*4096 + (size_t)lid*8;

  f4 acc[4][5];
#pragma unroll
  for (int mt=0; mt<4; ++mt)
#pragma unroll
    for (int nt=0; nt<5; ++nt){ f4 z = {0.f,0.f,0.f,0.f}; acc[mt][nt] = z; }

#pragma unroll
  for (int ks = 0; ks < 8; ++ks){
    s8 bv[5];
#pragma unroll
    for (int nt=0; nt<5; ++nt) bv[nt] = *(const s8*)(bp + (size_t)nt*4096 + ks*512);
#pragma unroll
    for (int mt=0; mt<4; ++mt){
      s8 av = *(const s8*)(ap + (size_t)mt*4096 + ks*512);
#pragma unroll
      for (int nt=0; nt<5; ++nt)
        acc[mt][nt] = __builtin_amdgcn_mfma_f32_16x16x32_bf16(av, bv[nt], acc[mt][nt], 0, 0, 0);
    }
  }

  /* bias + BN partial sums (8 spread copies -> low atomic contention) */
#pragma unroll
  for (int nt=0; nt<5; ++nt){
    int o = nt*16 + l15;
    float bias = (o < OUT_) ? b_experts[e*OUT_ + o] : 0.f;
    float s1 = 0.f, s2 = 0.f;
#pragma unroll
    for (int mt=0; mt<4; ++mt){
#pragma unroll
      for (int r=0; r<4; ++r){
        float vv = acc[mt][nt][r] + bias;
        acc[mt][nt][r] = vv;
        s1 += vv; s2 += vv*vv;
      }
    }
    s1 += __shfl_xor(s1, 16); s1 += __shfl_xor(s1, 32);
    s2 += __shfl_xor(s2, 16); s2 += __shfl_xor(s2, 32);
    if (quad == 0) sh.bnp[(nt*16 + l15)*4 + w] = make_float2(s1, s2);
  }
  __syncthreads();
  if (t < OUT_){
    float2 a0 = sh.bnp[t*4+0], a1 = sh.bnp[t*4+1], a2 = sh.bnp[t*4+2], a3 = sh.bnp[t*4+3];
    atomicAdd(bnsum + (bid&7)*NPAD_ + t, a0.x+a1.x+a2.x+a3.x);
    atomicAdd(bnss  + (bid&7)*NPAD_ + t, a0.y+a1.y+a2.y+a3.y);
  }

  __threadfence();          /* release: bnsum/bnss visible device-wide */
  cg::this_grid().sync();
  __threadfence();          /* acquire: see all blocks' atomics */

  /* ---- Phase C: BN finalize ---- */
  if (t < OUT_){
    float s1 = 0.f, s2 = 0.f;
#pragma unroll
    for (int k = 0; k < 8; ++k){ s1 += bnsum[k*NPAD_ + t]; s2 += bnss[k*NPAD_ + t]; }
    const float invN = 1.f/(float)(B_*HW_);
    float mean = s1*invN;
    float var  = s2*invN - mean*mean;
    float sc   = gamma[t] / sqrtf(var + 1e-5f);
    sh.fin.ss[t] = make_float2(sc, beta[t] - mean*sc);
  }
  __syncthreads();

  float2 sv[5];
#pragma unroll
  for (int nt=0; nt<5; ++nt){
    int o = nt*16 + l15;
    sv[nt] = (o < OUT_) ? sh.fin.ss[o] : make_float2(0.f, 0.f);
  }
#pragma unroll
  for (int mt=0; mt<4; ++mt)
#pragma unroll
    for (int nt=0; nt<5; ++nt){
      f4 vvv = acc[mt][nt];
#pragma unroll
      for (int r=0; r<4; ++r) vvv[r] = vvv[r]*sv[nt].x + sv[nt].y;
      acc[mt][nt] = vvv;
    }

  /* per-128px half: regs -> lt(bf16) -> logits(coalesced) + softmax + prob */
  for (int h = 0; h < 2; ++h){
    __syncthreads();
    if ((w >> 1) == h){
      int px0 = (w & 1)*64;
#pragma unroll
      for (int mt=0; mt<4; ++mt)
#pragma unroll
        for (int nt=0; nt<5; ++nt){
          int o = nt*16 + l15;
          if (o < OUT_){
            uint2 st;
            st.x = pk(acc[mt][nt][0], acc[mt][nt][1]);
            st.y = pk(acc[mt][nt][2], acc[mt][nt][3]);
            *(uint2*)(sh.fin.lt + o*136 + px0 + mt*16 + quad*4) = st;
          }
        }
    }
    __syncthreads();

    /* logits: 512B-coalesced rows from lt */
    for (int idx = t; idx < OUT_*32; idx += 256){
      int o = idx >> 5, px4 = idx & 31;
      const uint16_t* lp = sh.fin.lt + o*136 + px4*4;
      float4 fo = make_float4(bf2f(lp[0]), bf2f(lp[1]), bf2f(lp[2]), bf2f(lp[3]));
      *(float4*)(out_logits + ((size_t)(b*OUT_ + o))*HW_ + pt*256 + h*128 + px4*4) = fo;
    }

    if (t < 128){
      float m = -1e30f;
      for (int o = 0; o < OUT_; ++o) m = fmaxf(m, bf2f(sh.fin.lt[o*136 + t]));
      float ssum = 0.f;
      for (int o = 0; o < OUT_; ++o) ssum += __expf(bf2f(sh.fin.lt[o*136 + t]) - m);
      float inv = 1.f/ssum;
      int P = pt*256 + h*128 + t;
      int hh = P >> 6, wd = P & 63;
      float* pb = out_prob + ((size_t)b << 18) + (size_t)(hh*8)*512 + (size_t)wd*8;
#pragma unroll
      for (int r1 = 0; r1 < 8; ++r1){
        float4 q0, q1;
        q0.x = __expf(bf2f(sh.fin.lt[(r1*8+0)*136+t])-m)*inv;
        q0.y = __expf(bf2f(sh.fin.lt[(r1*8+1)*136+t])-m)*inv;
        q0.z = __expf(bf2f(sh.fin.lt[(r1*8+2)*136+t])-m)*inv;
        q0.w = __expf(bf2f(sh.fin.lt[(r1*8+3)*136+t])-m)*inv;
        q1.x = __expf(bf2f(sh.fin.lt[(r1*8+4)*136+t])-m)*inv;
        q1.y = __expf(bf2f(sh.fin.lt[(r1*8+5)*136+t])-m)*inv;
        q1.z = __expf(bf2f(sh.fin.lt[(r1*8+6)*136+t])-m)*inv;
        q1.w = __expf(bf2f(sh.fin.lt[(r1*8+7)*136+t])-m)*inv;
        *(float4*)(pb + (size_t)r1*512)     = q0;
        *(float4*)(pb + (size_t)r1*512 + 4) = q1;
      }
    }
  }
}

/* ---------------- Fallback path (round-0 verified structure) -------------- */
__global__ __launch_bounds__(256) void k_gemm_fb(const uint16_t* __restrict__ xb,
                                                 const uint16_t* __restrict__ Wt,
                                                 const int* __restrict__ idx_ws,
                                                 const float* __restrict__ b_experts,
                                                 uint16_t* __restrict__ yb,
                                                 float* __restrict__ bnsum,
                                                 float* __restrict__ bnss){
  __shared__ float2 bnp[NPAD_*4];
  int bid = blockIdx.x;
  int b = bid >> 4, pt = bid & 15;
  int t = threadIdx.x;
  int w = t >> 6, lane = t & 63;
  int l15 = lane & 15, quad = lane >> 4;
  int lid = l15*4 + quad;
  int e = idx_ws[b];
  int p0 = pt*256 + w*64;
  const uint16_t* ap = xb + ((size_t)(b*256 + pt*16 + w*4))*4096 + (size_t)lid*8;
  const uint16_t* bp = Wt + (size_t)e*5*4096 + (size_t)lid*8;

  f4 acc[4][5];
#pragma unroll
  for (int mt=0; mt<4; ++mt)
#pragma unroll
    for (int nt=0; nt<5; ++nt){ f4 z = {0.f,0.f,0.f,0.f}; acc[mt][nt] = z; }

#pragma unroll
  for (int ks = 0; ks < 8; ++ks){
    s8 av[4], bv[5];
#pragma unroll
    for (int mt=0; mt<4; ++mt) av[mt] = *(const s8*)(ap + (size_t)mt*4096 + ks*512);
#pragma unroll
    for (int nt=0; nt<5; ++nt) bv[nt] = *(const s8*)(bp + (size_t)nt*4096 + ks*512);
#pragma unroll
    for (int mt=0; mt<4; ++mt)
#pragma unroll
      for (int nt=0; nt<5; ++nt)
        acc[mt][nt] = __builtin_amdgcn_mfma_f32_16x16x32_bf16(av[mt], bv[nt], acc[mt][nt], 0, 0, 0);
  }

#pragma unroll
  for (int nt=0; nt<5; ++nt){
    int o = nt*16 + l15;
    float bias = (o < OUT_) ? b_experts[e*OUT_ + o] : 0.f;
    float s1 = 0.f, s2 = 0.f;
#pragma unroll
    for (int mt=0; mt<4; ++mt){
#pragma unroll
      for (int r=0; r<4; ++r){
        float vv = acc[mt][nt][r] + bias;
        acc[mt][nt][r] = vv;
        s1 += vv; s2 += vv*vv;
      }
      if (o < OUT_){
        size_t base = ((size_t)(b*OUT_ + o))*HW_ + p0 + mt*16 + quad*4;
        uint2 st;
        st.x = pk(acc[mt][nt][0], acc[mt][nt][1]);
        st.y = pk(acc[mt][nt][2], acc[mt][nt][3]);
        *(uint2*)(yb + base) = st;
      }
    }
    s1 += __shfl_xor(s1, 16); s1 += __shfl_xor(s1, 32);
    s2 += __shfl_xor(s2, 16); s2 += __shfl_xor(s2, 32);
    if (quad == 0) bnp[(nt*16 + l15)*4 + w] = make_float2(s1, s2);
  }
  __syncthreads();
  if (t < OUT_){
    float2 a0 = bnp[t*4+0], a1 = bnp[t*4+1], a2 = bnp[t*4+2], a3 = bnp[t*4+3];
    atomicAdd(bnsum + (bid&7)*NPAD_ + t, a0.x+a1.x+a2.x+a3.x);
    atomicAdd(bnss  + (bid&7)*NPAD_ + t, a0.y+a1.y+a2.y+a3.y);
  }
}

__global__ __launch_bounds__(256) void k_final_fb(const uint16_t* __restrict__ yb,
                                                  const float* __restrict__ bnsum,
                                                  const float* __restrict__ bnss,
                                                  const float* __restrict__ gamma,
                                                  const float* __restrict__ beta,
                                                  float* __restrict__ out_logits,
                                                  float* __restrict__ out_prob){
  __shared__ float lt[OUT_*132];
  __shared__ float2 ss[OUT_];
  int bid = blockIdx.x;
  int b = bid >> 5, pt = bid & 31;
  int p0 = pt*128;
  int t = threadIdx.x;
  if (t < OUT_){
    float s1 = 0.f, s2 = 0.f;
#pragma unroll
    for (int k = 0; k < 8; ++k){ s1 += bnsum[k*NPAD_ + t]; s2 += bnss[k*NPAD_ + t]; }
    const float invN = 1.f/(float)(B_*HW_);
    float mean = s1*invN;
    float var  = s2*invN - mean*mean;
    float sc   = gamma[t] / sqrtf(var + 1e-5f);
    ss[t] = make_float2(sc, beta[t] - mean*sc);
  }
  __syncthreads();

  int prr = t & 15, og = t >> 4;
#pragma unroll
  for (int oi = 0; oi < 5; ++oi){
    int o = og + oi*16;
    if (o < OUT_){
      size_t base = ((size_t)(b*OUT_ + o))*HW_ + p0 + prr*8;
      uint4 raw = *(const uint4*)(yb + base);
      float f[8];
      f[0]=bf2f(raw.x); f[1]=bf2f(raw.x>>16);
      f[2]=bf2f(raw.y); f[3]=bf2f(raw.y>>16);
      f[4]=bf2f(raw.z); f[5]=bf2f(raw.z>>16);
      f[6]=bf2f(raw.w); f[7]=bf2f(raw.w>>16);
      float2 sv = ss[o];
#pragma unroll
      for (int k=0;k<8;++k) f[k] = f[k]*sv.x + sv.y;
      float4 w0 = make_float4(f[0],f[1],f[2],f[3]);
      float4 w1 = make_float4(f[4],f[5],f[6],f[7]);
      *(float4*)(out_logits + base)     = w0;
      *(float4*)(out_logits + base + 4) = w1;
      float* lp = lt + o*132 + prr*8;
      *(float4*)(lp)     = w0;
      *(float4*)(lp + 4) = w1;
    }
  }
  __syncthreads();

  if (t < 128){
    float m = -1e30f;
    for (int o = 0; o < OUT_; ++o) m = fmaxf(m, lt[o*132 + t]);
    float ssum = 0.f;
    for (int o = 0; o < OUT_; ++o) ssum += __expf(lt[o*132 + t] - m);
    float inv = 1.f/ssum;
    int P = p0 + t;
    int h = P >> 6, wd = P & 63;
    float* pb = out_prob + ((size_t)b << 18) + (size_t)(h*8)*512 + (size_t)wd*8;
#pragma unroll
    for (int r1 = 0; r1 < 8; ++r1){
      float4 q0, q1;
      q0.x = __expf(lt[(r1*8+0)*132+t]-m)*inv;
      q0.y = __expf(lt[(r1*8+1)*132+t]-m)*inv;
      q0.z = __expf(lt[(r1*8+2)*132+t]-m)*inv;
      q0.w = __expf(lt[(r1*8+3)*132+t]-m)*inv;
      q1.x = __expf(lt[(r1*8+4)*132+t]-m)*inv;
      q1.y = __expf(lt[(r1*8+5)*132+t]-m)*inv;
      q1.z = __expf(lt[(r1*8+6)*132+t]-m)*inv;
      q1.w = __expf(lt[(r1*8+7)*132+t]-m)*inv;
      *(float4*)(pb + r1*512)     = q0;
      *(float4*)(pb + r1*512 + 4) = q1;
    }
  }
}

extern "C" void kernel_launch(void* const* d_in, const int* in_sizes, int n_in,
                              void* d_out, int out_size, void* d_ws, size_t ws_size,
                              hipStream_t stream){
  const float* x         = (const float*)d_in[0];
  const float* w_experts = (const float*)d_in[1];
  const float* b_experts = (const float*)d_in[2];
  const float* w_gate    = (const float*)d_in[3];
  const float* b_gate    = (const float*)d_in[4];
  const float* gamma     = (const float*)d_in[5];
  const float* beta      = (const float*)d_in[6];

  float* out = (float*)d_out;
  char*  ws  = (char*)d_ws;
  float*     pooled = (float*)(ws + POOLED_OFF);
  int*       idxw   = (int*)(ws + IDX_OFF);
  float*     bnsum  = (float*)(ws + BNS_OFF);
  float*     bnss   = (float*)(ws + BNSS_OFF);
  uint16_t*  Wt     = (uint16_t*)(ws + WT_OFF);
  uint16_t*  ybm    = (uint16_t*)(ws + YB_OFF);
  /* xb (128 MiB, bf16 tiled) lives in d_out: fully consumed before the
     post-sync phase overwrites d_out with logits/prob. */
  uint16_t*  xbm    = (uint16_t*)d_out;

  float* logits = out;
  float* prob   = out + LOGITS_SZ;
  float* lbp    = out + LOGITS_SZ + PROB_SZ;

  hipMemsetAsync(ws, 0, CLEAR_BYTES, stream);
  k_prep<<<8512, 256, 0, stream>>>(x, w_experts, xbm, Wt, pooled);
  k_lb<<<1, 256, 0, stream>>>(pooled, w_gate, b_gate, idxw, lbp);

  void* args[] = { (void*)&xbm, (void*)&Wt, (void*)&idxw, (void*)&b_experts,
                   (void*)&gamma, (void*)&beta, (void*)&bnsum, (void*)&bnss,
                   (void*)&logits, (void*)&prob };
  hipError_t cerr = hipLaunchCooperativeKernel((void*)k_fused, dim3(1024),
                                               dim3(256), args, 0, stream);
  if (cerr != hipSuccess){
    /* cooperative launch rejected -> known-good split pipeline */
    k_gemm_fb <<<1024, 256, 0, stream>>>(xbm, Wt, idxw, b_experts, ybm, bnsum, bnss);
    k_final_fb<<<2048, 256, 0, stream>>>(ybm, bnsum, bnss, gamma, beta, logits, prob);
  }
}

// Round 3
// 488.204 us; speedup vs baseline: 1.5151x; 1.5151x over previous
//
#include <hip/hip_runtime.h>
#include <stdint.h>
#include <math.h>

#define B_    64
#define C_    256
#define HW_   4096
#define E_    4
#define OUT_  65
#define NPAD_ 80
#define NSPREAD_ 16

#define LOGITS_SZ (B_*OUT_*HW_)   /* 17,039,360 */
#define PROB_SZ   (B_*512*512)    /* 16,777,216 */

/* ws byte offsets */
#define POOLED_OFF 0u         /* 64*256 f32 = 65536 */
#define BNS_OFF    65536u     /* 16 spread copies x 80 f32 = 5120 */
#define BNSS_OFF   70656u     /* 16 x 80 f32 = 5120 */
#define CLEAR_BYTES 75776u
#define WT_OFF     75776u     /* 4*5*8*64*8 bf16 = 163840 */
#define YB_OFF     239616u    /* 64*65*4096 bf16 = 34,078,720 */

typedef float  f4 __attribute__((ext_vector_type(4)));
typedef short  s8 __attribute__((ext_vector_type(8)));

__device__ __forceinline__ uint32_t f2bf(float f){
  uint32_t u = __float_as_uint(f);
  return (u + 0x7FFFu + ((u >> 16) & 1u)) >> 16;
}
__device__ __forceinline__ uint32_t pk(float lo, float hi){
  return f2bf(lo) | (f2bf(hi) << 16);
}
__device__ __forceinline__ float bf2f(uint32_t u){
  return __uint_as_float((u & 0xFFFFu) << 16);
}

/* xb tiled layout (MFMA A-fragment order):
   elem(p, c) -> [b][T=p>>4][ks=c>>5][lane=(p&15)*4 + ((c>>3)&3)][j=c&7] */

/* ---------------- K1: relu + pool(sum) + transpose-to-bf16 + Wt pack ------ */
/* grid 8512: blocks <8192 prep (64b*4ct*32pt); blocks >=8192: Wt pack. */
__global__ __launch_bounds__(256) void k_prep(const float* __restrict__ x,
                                              const float* __restrict__ w_experts,
                                              uint16_t* __restrict__ xb,
                                              uint16_t* __restrict__ Wt,
                                              float* __restrict__ pooled){
  __shared__ float pool_lds[64];
  int bid = blockIdx.x;
  int t = threadIdx.x;

  if (bid >= 8192){
    if (t >= 32) return;
    int pid = bid - 8192;
    int e = pid / NPAD_, o = pid % NPAD_;
    int ks = t >> 2, quad = t & 3;
    int c = t*8;
    float a[8];
    if (o < OUT_){
      const float* src = w_experts + (size_t)e*C_*OUT_ + o;
#pragma unroll
      for (int j = 0; j < 8; ++j) a[j] = src[(size_t)(c+j)*OUT_];
    } else {
#pragma unroll
      for (int j = 0; j < 8; ++j) a[j] = 0.f;
    }
    uint4 wv;
    wv.x = pk(a[0],a[1]); wv.y = pk(a[2],a[3]);
    wv.z = pk(a[4],a[5]); wv.w = pk(a[6],a[7]);
    uint16_t* dst = Wt + ((((size_t)(e*5 + (o>>4))*8 + ks)*64)
                          + (size_t)((o&15)*4 + quad))*8;
    *(uint4*)dst = wv;
    return;
  }

  int b = bid >> 7, ct = (bid >> 5) & 3, pt = bid & 31;
  int cg_ = t & 7, pgg = t >> 3;
  int c0 = ct*64 + cg_*8;
  int p0 = pt*128 + pgg*4;
  if (t < 64) pool_lds[t] = 0.f;
  __syncthreads();

  float v[8][4]; float s[8];
  const float* xp = x + ((size_t)(b*C_ + c0))*HW_ + p0;
#pragma unroll
  for (int r = 0; r < 8; ++r){
    float4 f = *(const float4*)(xp + (size_t)r*HW_);
    v[r][0]=fmaxf(f.x,0.f); v[r][1]=fmaxf(f.y,0.f);
    v[r][2]=fmaxf(f.z,0.f); v[r][3]=fmaxf(f.w,0.f);
    s[r] = v[r][0]+v[r][1]+v[r][2]+v[r][3];
  }
  int ksg  = ct*2 + (cg_ >> 2);
  int quad = cg_ & 3;
  /* p0..p0+3 stay within one 16-px tile (p0%4==0, (p0&15)<=12), so
     dst advances by 32 elems (4 lanes) per pp — compute base once. */
  uint16_t* dst0 = xb + ((((size_t)(b*256 + (p0>>4))*8 + ksg)*64)
                         + (size_t)((p0&15)*4 + quad))*8;
#pragma unroll
  for (int pp = 0; pp < 4; ++pp){
    uint4 w;
    w.x = pk(v[0][pp], v[1][pp]); w.y = pk(v[2][pp], v[3][pp]);
    w.z = pk(v[4][pp], v[5][pp]); w.w = pk(v[6][pp], v[7][pp]);
    *(uint4*)(dst0 + pp*32) = w;
  }
#pragma unroll
  for (int r = 0; r < 8; ++r){
    float vv = s[r];
    vv += __shfl_xor(vv, 8);
    vv += __shfl_xor(vv, 16);
    vv += __shfl_xor(vv, 32);
    if ((t & 56) == 0)
      atomicAdd(&pool_lds[cg_*8 + r], vv);
  }
  __syncthreads();
  if (t < 64) atomicAdd(pooled + b*C_ + ct*64 + t, pool_lds[t]);
}

/* ---------------- K2: inline gate + bf16 MFMA GEMM + bias + BN partials --- */
/* grid 2048 = 64b * 32pt(128px); block 256 = 4 waves; wave: 32 px (2 Mtiles)
   x 5 N-strips. acc[2][5] keeps regs ~100 -> 4+ blocks/CU. */
__global__ __launch_bounds__(256) void k_gemm(const uint16_t* __restrict__ xb,
                                              const uint16_t* __restrict__ Wt,
                                              const float* __restrict__ pooled,
                                              const float* __restrict__ w_gate,
                                              const float* __restrict__ b_gate,
                                              const float* __restrict__ b_experts,
                                              uint16_t* __restrict__ yb,
                                              float* __restrict__ bnsum,
                                              float* __restrict__ bnss){
  __shared__ float2 bnp[NPAD_*4];
  __shared__ float glog[4];
  __shared__ int esh;
  int bid = blockIdx.x;
  int b = bid >> 5, pt = bid & 31;
  int t = threadIdx.x;
  int w = t >> 6, lane = t & 63;
  int l15 = lane & 15, quad = lane >> 4;
  int lid = l15*4 + quad;

  /* gate: 4 threads, serial dot — same order/op sequence as k_final's lb
     recompute, so the argmax is bitwise-consistent across kernels. */
  if (t < 4){
    float dot = 0.f;
    const float* pr = pooled + b*C_;
    for (int c = 0; c < C_; c += 4){
      float4 p4 = *(const float4*)(pr + c);
      dot += p4.x*w_gate[c*4+t] + p4.y*w_gate[(c+1)*4+t]
           + p4.z*w_gate[(c+2)*4+t] + p4.w*w_gate[(c+3)*4+t];
    }
    glog[t] = dot * (1.f/4096.f) + b_gate[t];
  }
  __syncthreads();
  if (t == 0){
    float best = glog[0]; int bi = 0;
#pragma unroll
    for (int ee = 1; ee < 4; ++ee){ float vv = glog[ee]; if (vv > best){best = vv; bi = ee;} }
    esh = bi;
  }
  __syncthreads();
  int e = esh;

  int p0 = pt*128 + w*32;
  const uint16_t* ap = xb + ((size_t)(b*256 + pt*8 + w*2))*4096 + (size_t)lid*8;
  const uint16_t* bp = Wt + (size_t)e*5*4096 + (size_t)lid*8;

  f4 acc[2][5];
#pragma unroll
  for (int mt=0; mt<2; ++mt)
#pragma unroll
    for (int nt=0; nt<5; ++nt){ f4 z = {0.f,0.f,0.f,0.f}; acc[mt][nt] = z; }

#pragma unroll
  for (int ks = 0; ks < 8; ++ks){
    s8 bv[5];
#pragma unroll
    for (int nt=0; nt<5; ++nt) bv[nt] = *(const s8*)(bp + (size_t)nt*4096 + ks*512);
#pragma unroll
    for (int mt=0; mt<2; ++mt){
      s8 av = *(const s8*)(ap + (size_t)mt*4096 + ks*512);
#pragma unroll
      for (int nt=0; nt<5; ++nt)
        acc[mt][nt] = __builtin_amdgcn_mfma_f32_16x16x32_bf16(av, bv[nt], acc[mt][nt], 0, 0, 0);
    }
  }

#pragma unroll
  for (int nt=0; nt<5; ++nt){
    int o = nt*16 + l15;
    float bias = (o < OUT_) ? b_experts[e*OUT_ + o] : 0.f;
    float s1 = 0.f, s2 = 0.f;
#pragma unroll
    for (int mt=0; mt<2; ++mt){
#pragma unroll
      for (int r=0; r<4; ++r){
        float vv = acc[mt][nt][r] + bias;
        acc[mt][nt][r] = vv;
        s1 += vv; s2 += vv*vv;
      }
      if (o < OUT_){
        size_t base = ((size_t)(b*OUT_ + o))*HW_ + p0 + mt*16 + quad*4;
        uint2 st;
        st.x = pk(acc[mt][nt][0], acc[mt][nt][1]);
        st.y = pk(acc[mt][nt][2], acc[mt][nt][3]);
        *(uint2*)(yb + base) = st;
      }
    }
    s1 += __shfl_xor(s1, 16); s1 += __shfl_xor(s1, 32);
    s2 += __shfl_xor(s2, 16); s2 += __shfl_xor(s2, 32);
    if (quad == 0) bnp[(nt*16 + l15)*4 + w] = make_float2(s1, s2);
  }
  __syncthreads();
  if (t < OUT_){
    float2 a0 = bnp[t*4+0], a1 = bnp[t*4+1], a2 = bnp[t*4+2], a3 = bnp[t*4+3];
    atomicAdd(bnsum + (bid & (NSPREAD_-1))*NPAD_ + t, a0.x+a1.x+a2.x+a3.x);
    atomicAdd(bnss  + (bid & (NSPREAD_-1))*NPAD_ + t, a0.y+a1.y+a2.y+a3.y);
  }
}

/* ---------------- K3: BN finalize + logits + softmax + shuffle + lb ------- */
/* grid 2048 = 64b * 32pt(128px); block 256. All 256 threads work the
   softmax (2 threads/px, o-range split 33/32); exp stored back into lt
   (no recompute); no max-subtraction (logits are BN-normalized, |l|<~10). */
__global__ __launch_bounds__(256) void k_final(const uint16_t* __restrict__ yb,
                                               const float* __restrict__ bnsum,
                                               const float* __restrict__ bnss,
                                               const float* __restrict__ gamma,
                                               const float* __restrict__ beta,
                                               const float* __restrict__ pooled,
                                               const float* __restrict__ w_gate,
                                               const float* __restrict__ b_gate,
                                               float* __restrict__ out_logits,
                                               float* __restrict__ out_prob,
                                               float* __restrict__ out_lb){
  __shared__ float lt[OUT_*132];
  __shared__ float2 ss[OUT_];
  __shared__ float sden[256];
  __shared__ float gl[64][4];
  __shared__ int ish[64];
  int bid = blockIdx.x;
  int b = bid >> 5, pt = bid & 31;
  int p0 = pt*128;
  int t = threadIdx.x;
  if (t < OUT_){
    float s1 = 0.f, s2 = 0.f;
#pragma unroll
    for (int k = 0; k < NSPREAD_; ++k){ s1 += bnsum[k*NPAD_ + t]; s2 += bnss[k*NPAD_ + t]; }
    const float invN = 1.f/(float)(B_*HW_);
    float mean = s1*invN;
    float var  = s2*invN - mean*mean;
    float sc   = gamma[t] / sqrtf(var + 1e-5f);
    ss[t] = make_float2(sc, beta[t] - mean*sc);
  }
  __syncthreads();

  int prr = t & 15, og = t >> 4;
#pragma unroll
  for (int oi = 0; oi < 5; ++oi){
    int o = og + oi*16;
    if (o < OUT_){
      size_t base = ((size_t)(b*OUT_ + o))*HW_ + p0 + prr*8;
      uint4 raw = *(const uint4*)(yb + base);
      float f[8];
      f[0]=bf2f(raw.x); f[1]=bf2f(raw.x>>16);
      f[2]=bf2f(raw.y); f[3]=bf2f(raw.y>>16);
      f[4]=bf2f(raw.z); f[5]=bf2f(raw.z>>16);
      f[6]=bf2f(raw.w); f[7]=bf2f(raw.w>>16);
      float2 sv = ss[o];
#pragma unroll
      for (int k=0;k<8;++k) f[k] = f[k]*sv.x + sv.y;
      float4 w0 = make_float4(f[0],f[1],f[2],f[3]);
      float4 w1 = make_float4(f[4],f[5],f[6],f[7]);
      *(float4*)(out_logits + base)     = w0;
      *(float4*)(out_logits + base + 4) = w1;
      float* lp = lt + o*132 + prr*8;
      *(float4*)(lp)     = w0;
      *(float4*)(lp + 4) = w1;
    }
  }
  __syncthreads();

  /* exp phase: 2 threads per px, write exp back into lt */
  int px = t & 127, hf = t >> 7;
  {
    int obeg = hf ? 33 : 0, oend = hf ? OUT_ : 33;
    float ssum = 0.f;
    for (int o = obeg; o < oend; ++o){
      float ev = __expf(lt[o*132 + px]);
      lt[o*132 + px] = ev;
      ssum += ev;
    }
    sden[hf*128 + px] = ssum;
  }
  __syncthreads();
  {
    float inv = 1.f/(sden[px] + sden[128 + px]);
    int P = p0 + px;
    int hh = P >> 6, wd = P & 63;
    float* pb = out_prob + ((size_t)b << 18) + (size_t)(hh*8)*512 + (size_t)wd*8;
#pragma unroll
    for (int r1i = 0; r1i < 4; ++r1i){
      int r1 = hf*4 + r1i;
      float4 q0, q1;
      q0.x = lt[(r1*8+0)*132+px]*inv;
      q0.y = lt[(r1*8+1)*132+px]*inv;
      q0.z = lt[(r1*8+2)*132+px]*inv;
      q0.w = lt[(r1*8+3)*132+px]*inv;
      q1.x = lt[(r1*8+4)*132+px]*inv;
      q1.y = lt[(r1*8+5)*132+px]*inv;
      q1.z = lt[(r1*8+6)*132+px]*inv;
      q1.w = lt[(r1*8+7)*132+px]*inv;
      *(float4*)(pb + (size_t)r1*512)     = q0;
      *(float4*)(pb + (size_t)r1*512 + 4) = q1;
    }
  }

  /* lb_loss: block 0 recomputes all 64 gates (same serial order as k_gemm) */
  if (bid == 0){
    __syncthreads();
    int bb = t >> 2, ee = t & 3;
    float dot = 0.f;
    const float* pr = pooled + bb*C_;
    for (int c = 0; c < C_; c += 4){
      float4 p4 = *(const float4*)(pr + c);
      dot += p4.x*w_gate[c*4+ee] + p4.y*w_gate[(c+1)*4+ee]
           + p4.z*w_gate[(c+2)*4+ee] + p4.w*w_gate[(c+3)*4+ee];
    }
    gl[bb][ee] = dot * (1.f/4096.f) + b_gate[ee];
    __syncthreads();
    if (t < 64){
      float best = gl[t][0]; int bi = 0;
#pragma unroll
      for (int e2 = 1; e2 < 4; ++e2){ float vv = gl[t][e2]; if (vv > best){best = vv; bi = e2;} }
      ish[t] = bi;
    }
    __syncthreads();
    if (t == 0){
      int cnt[4] = {0,0,0,0};
      for (int b2 = 0; b2 < 64; ++b2) cnt[ish[b2]]++;
      double u[4], S = 0.0;
      for (int e2 = 0; e2 < 4; ++e2){ u[e2] = cnt[e2]/64.0 + 1e-6; S += u[e2]; }
      double lbv = 0.0;
      for (int e2 = 0; e2 < 4; ++e2){ double uu = u[e2]/S; lbv += uu*(log(uu) - log(0.25)); }
      *out_lb = (float)lbv;
    }
  }
}

extern "C" void kernel_launch(void* const* d_in, const int* in_sizes, int n_in,
                              void* d_out, int out_size, void* d_ws, size_t ws_size,
                              hipStream_t stream){
  const float* x         = (const float*)d_in[0];
  const float* w_experts = (const float*)d_in[1];
  const float* b_experts = (const float*)d_in[2];
  const float* w_gate    = (const float*)d_in[3];
  const float* b_gate    = (const float*)d_in[4];
  const float* gamma     = (const float*)d_in[5];
  const float* beta      = (const float*)d_in[6];

  float* out = (float*)d_out;
  char*  ws  = (char*)d_ws;
  float*     pooled = (float*)(ws + POOLED_OFF);
  float*     bnsum  = (float*)(ws + BNS_OFF);
  float*     bnss   = (float*)(ws + BNSS_OFF);
  uint16_t*  Wt     = (uint16_t*)(ws + WT_OFF);
  uint16_t*  ybm    = (uint16_t*)(ws + YB_OFF);
  /* xb (128 MiB, bf16 tiled) lives in d_out: fully consumed by k_gemm
     before k_final overwrites d_out with logits/prob. */
  uint16_t*  xbm    = (uint16_t*)d_out;

  float* logits = out;
  float* prob   = out + LOGITS_SZ;
  float* lbp    = out + LOGITS_SZ + PROB_SZ;

  hipMemsetAsync(ws, 0, CLEAR_BYTES, stream);
  k_prep <<<8512, 256, 0, stream>>>(x, w_experts, xbm, Wt, pooled);
  k_gemm <<<2048, 256, 0, stream>>>(xbm, Wt, pooled, w_gate, b_gate, b_experts,
                                    ybm, bnsum, bnss);
  k_final<<<2048, 256, 0, stream>>>(ybm, bnsum, bnss, gamma, beta,
                                    pooled, w_gate, b_gate, logits, prob, lbp);
}

// Round 5
// 477.953 us; speedup vs baseline: 1.5476x; 1.0214x over previous
//
#include <hip/hip_runtime.h>
#include <stdint.h>
#include <math.h>

#define B_    64
#define C_    256
#define HW_   4096
#define E_    4
#define OUT_  65
#define NPAD_ 80
#define NSPREAD_ 16

#define LOGITS_SZ (B_*OUT_*HW_)   /* 17,039,360 */
#define PROB_SZ   (B_*512*512)    /* 16,777,216 */

/* ws byte offsets (no memset: everything below is fully store-initialized
   each iteration, except bnsum/bnss which k_prep's block 8192 zeroes). */
#define PP_OFF    0u          /* pooled partials [64][32][256] f32 = 2 MB */
#define ESEL_OFF  2097152u    /* 64 i32 */
#define BNS_OFF   2097408u    /* 16*80 f32 = 5120 B */
#define BNSS_OFF  2102528u    /* 16*80 f32 = 5120 B */
#define WT_OFF    2107648u    /* 4*5*8*64*8 bf16 = 163840 B */
#define YB_OFF    2271488u    /* 64*65*4096 bf16 = 34,078,720 B */

typedef float  f4 __attribute__((ext_vector_type(4)));
typedef short  s8 __attribute__((ext_vector_type(8)));

__device__ __forceinline__ uint32_t f2bf(float f){
  uint32_t u = __float_as_uint(f);
  return (u + 0x7FFFu + ((u >> 16) & 1u)) >> 16;
}
__device__ __forceinline__ uint32_t pk(float lo, float hi){
  return f2bf(lo) | (f2bf(hi) << 16);
}
__device__ __forceinline__ float bf2f(uint32_t u){
  return __uint_as_float((u & 0xFFFFu) << 16);
}

/* xb tiled layout (MFMA A-fragment order):
   elem(p, c) -> [b][T=p>>4][ks=c>>5][lane=(p&15)*4 + ((c>>3)&3)][j=c&7] */

/* ---------------- K1: relu + pool-partials + bf16 transpose + Wt + bnzero - */
/* grid 8512: blocks <8192 prep (64b*4ct*32pt); blocks >=8192: Wt pack
   (block 8192's spare threads zero bnsum/bnss for k_gemm's atomics). */
__global__ __launch_bounds__(256) void k_prep(const float* __restrict__ x,
                                              const float* __restrict__ w_experts,
                                              uint16_t* __restrict__ xb,
                                              uint16_t* __restrict__ Wt,
                                              float* __restrict__ pp,
                                              float* __restrict__ bnz){
  __shared__ float pool_lds[64];
  int bid = blockIdx.x;
  int t = threadIdx.x;

  if (bid >= 8192){
    if (bid == 8192 && t >= 32){
      /* zero bnsum+bnss (contiguous 2*16*80 f32) — consumed by k_gemm only */
      for (int i = t - 32; i < 2*NSPREAD_*NPAD_; i += 224) bnz[i] = 0.f;
    }
    if (t >= 32) return;
    int pid = bid - 8192;
    int e = pid / NPAD_, o = pid % NPAD_;
    int ks = t >> 2, quad = t & 3;
    int c = t*8;
    float a[8];
    if (o < OUT_){
      const float* src = w_experts + (size_t)e*C_*OUT_ + o;
#pragma unroll
      for (int j = 0; j < 8; ++j) a[j] = src[(size_t)(c+j)*OUT_];
    } else {
#pragma unroll
      for (int j = 0; j < 8; ++j) a[j] = 0.f;
    }
    uint4 wv;
    wv.x = pk(a[0],a[1]); wv.y = pk(a[2],a[3]);
    wv.z = pk(a[4],a[5]); wv.w = pk(a[6],a[7]);
    uint16_t* dst = Wt + ((((size_t)(e*5 + (o>>4))*8 + ks)*64)
                          + (size_t)((o&15)*4 + quad))*8;
    *(uint4*)dst = wv;
    return;
  }

  int b = bid >> 7, ct = (bid >> 5) & 3, pt = bid & 31;
  int cg_ = t & 7, pgg = t >> 3;
  int c0 = ct*64 + cg_*8;
  int p0 = pt*128 + pgg*4;
  if (t < 64) pool_lds[t] = 0.f;
  __syncthreads();

  float v[8][4]; float s[8];
  const float* xp = x + ((size_t)(b*C_ + c0))*HW_ + p0;
#pragma unroll
  for (int r = 0; r < 8; ++r){
    f4 f = __builtin_nontemporal_load((const f4*)(xp + (size_t)r*HW_));
    v[r][0]=fmaxf(f[0],0.f); v[r][1]=fmaxf(f[1],0.f);
    v[r][2]=fmaxf(f[2],0.f); v[r][3]=fmaxf(f[3],0.f);
    s[r] = v[r][0]+v[r][1]+v[r][2]+v[r][3];
  }
  int ksg  = ct*2 + (cg_ >> 2);
  int quad = cg_ & 3;
  /* p0..p0+3 stay within one 16-px tile -> dst advances 32 elems per pp. */
  uint16_t* dst0 = xb + ((((size_t)(b*256 + (p0>>4))*8 + ksg)*64)
                         + (size_t)((p0&15)*4 + quad))*8;
#pragma unroll
  for (int pi = 0; pi < 4; ++pi){
    uint4 w;
    w.x = pk(v[0][pi], v[1][pi]); w.y = pk(v[2][pi], v[3][pi]);
    w.z = pk(v[4][pi], v[5][pi]); w.w = pk(v[6][pi], v[7][pi]);
    *(uint4*)(dst0 + pi*32) = w;
  }
#pragma unroll
  for (int r = 0; r < 8; ++r){
    float vv = s[r];
    vv += __shfl_xor(vv, 8);
    vv += __shfl_xor(vv, 16);
    vv += __shfl_xor(vv, 32);
    if ((t & 56) == 0)
      atomicAdd(&pool_lds[cg_*8 + r], vv);
  }
  __syncthreads();
  /* partial store (no global atomics, no pre-zero): pp[b][pt][ct*64+t] */
  if (t < 64) pp[((size_t)(b*32 + pt))*256 + ct*64 + t] = pool_lds[t];
}

/* ---------------- K2: gate-from-partials + bf16 MFMA GEMM + BN partials --- */
/* grid 2048 = 64b * 32pt(128px); block 256 = 4 waves.
   Gate: all blocks of batch b run identical code on identical bits ->
   identical logits -> identical argmax. pt==0 block publishes esel[b]. */
__global__ __launch_bounds__(256) void k_gemm(const uint16_t* __restrict__ xb,
                                              const uint16_t* __restrict__ Wt,
                                              const float* __restrict__ pp,
                                              const float* __restrict__ w_gate,
                                              const float* __restrict__ b_gate,
                                              const float* __restrict__ b_experts,
                                              uint16_t* __restrict__ yb,
                                              float* __restrict__ bnsum,
                                              float* __restrict__ bnss,
                                              int* __restrict__ esel){
  __shared__ float2 bnp[NPAD_*4];
  __shared__ float glp[64][4];
  __shared__ int esh;
  int bid = blockIdx.x;
  int b = bid >> 5, pt = bid & 31;
  int t = threadIdx.x;
  int w = t >> 6, lane = t & 63;
  int l15 = lane & 15, quad = lane >> 4;
  int lid = l15*4 + quad;

  /* gate: thread (ee, cgp) sums 32 pt-partials for 4 c's, dots w_gate */
  {
    int ee = t & 3, cgp = t >> 2;
    const float* ppb = pp + ((size_t)b*32)*256 + cgp*4;
    float4 sa = make_float4(0.f,0.f,0.f,0.f);
    for (int ptk = 0; ptk < 32; ++ptk){
      float4 vv = *(const float4*)(ppb + ptk*256);
      sa.x += vv.x; sa.y += vv.y; sa.z += vv.z; sa.w += vv.w;
    }
    int c0 = cgp*4;
    glp[cgp][ee] = sa.x*w_gate[(c0+0)*4+ee] + sa.y*w_gate[(c0+1)*4+ee]
                 + sa.z*w_gate[(c0+2)*4+ee] + sa.w*w_gate[(c0+3)*4+ee];
  }
  __syncthreads();
  if (t < 4){
    float sg = 0.f;
    for (int g = 0; g < 64; ++g) sg += glp[g][t];     /* fixed order */
    glp[0][t] = sg * (1.f/4096.f) + b_gate[t];
  }
  __syncthreads();
  if (t == 0){
    float best = glp[0][0]; int bi = 0;
#pragma unroll
    for (int ee = 1; ee < 4; ++ee){ float vv = glp[0][ee]; if (vv > best){best = vv; bi = ee;} }
    esh = bi;
    if (pt == 0) esel[b] = bi;
  }
  __syncthreads();
  int e = esh;

  int p0 = pt*128 + w*32;
  const uint16_t* ap = xb + ((size_t)(b*256 + pt*8 + w*2))*4096 + (size_t)lid*8;
  const uint16_t* bp = Wt + (size_t)e*5*4096 + (size_t)lid*8;

  f4 acc[2][5];
#pragma unroll
  for (int mt=0; mt<2; ++mt)
#pragma unroll
    for (int nt=0; nt<5; ++nt){ f4 z = {0.f,0.f,0.f,0.f}; acc[mt][nt] = z; }

#pragma unroll
  for (int ks = 0; ks < 8; ++ks){
    s8 bv[5];
#pragma unroll
    for (int nt=0; nt<5; ++nt) bv[nt] = *(const s8*)(bp + (size_t)nt*4096 + ks*512);
#pragma unroll
    for (int mt=0; mt<2; ++mt){
      s8 av = *(const s8*)(ap + (size_t)mt*4096 + ks*512);
#pragma unroll
      for (int nt=0; nt<5; ++nt)
        acc[mt][nt] = __builtin_amdgcn_mfma_f32_16x16x32_bf16(av, bv[nt], acc[mt][nt], 0, 0, 0);
    }
  }

#pragma unroll
  for (int nt=0; nt<5; ++nt){
    int o = nt*16 + l15;
    float bias = (o < OUT_) ? b_experts[e*OUT_ + o] : 0.f;
    float s1 = 0.f, s2 = 0.f;
#pragma unroll
    for (int mt=0; mt<2; ++mt){
#pragma unroll
      for (int r=0; r<4; ++r){
        float vv = acc[mt][nt][r] + bias;
        acc[mt][nt][r] = vv;
        s1 += vv; s2 += vv*vv;
      }
      if (o < OUT_){
        size_t base = ((size_t)(b*OUT_ + o))*HW_ + p0 + mt*16 + quad*4;
        uint2 st;
        st.x = pk(acc[mt][nt][0], acc[mt][nt][1]);
        st.y = pk(acc[mt][nt][2], acc[mt][nt][3]);
        *(uint2*)(yb + base) = st;
      }
    }
    s1 += __shfl_xor(s1, 16); s1 += __shfl_xor(s1, 32);
    s2 += __shfl_xor(s2, 16); s2 += __shfl_xor(s2, 32);
    if (quad == 0) bnp[(nt*16 + l15)*4 + w] = make_float2(s1, s2);
  }
  __syncthreads();
  if (t < OUT_){
    float2 a0 = bnp[t*4+0], a1 = bnp[t*4+1], a2 = bnp[t*4+2], a3 = bnp[t*4+3];
    atomicAdd(bnsum + (bid & (NSPREAD_-1))*NPAD_ + t, a0.x+a1.x+a2.x+a3.x);
    atomicAdd(bnss  + (bid & (NSPREAD_-1))*NPAD_ + t, a0.y+a1.y+a2.y+a3.y);
  }
}

/* ---------------- K3: BN finalize + logits + softmax + shuffle + lb ------- */
/* grid 2048 = 64b * 32pt(128px); block 256. lt is bf16 (17.7 KB LDS ->
   8 blocks/CU). exp split 2 threads/px; lb from esel counts (block 0). */
__global__ __launch_bounds__(256) void k_final(const uint16_t* __restrict__ yb,
                                               const float* __restrict__ bnsum,
                                               const float* __restrict__ bnss,
                                               const float* __restrict__ gamma,
                                               const float* __restrict__ beta,
                                               const int* __restrict__ esel,
                                               float* __restrict__ out_logits,
                                               float* __restrict__ out_prob,
                                               float* __restrict__ out_lb){
  __shared__ uint16_t lt[OUT_*136];
  __shared__ float2 ss[OUT_];
  __shared__ float sden[256];
  __shared__ int ish[64];
  int bid = blockIdx.x;
  int b = bid >> 5, pt = bid & 31;
  int p0 = pt*128;
  int t = threadIdx.x;
  if (t < OUT_){
    float s1 = 0.f, s2 = 0.f;
#pragma unroll
    for (int k = 0; k < NSPREAD_; ++k){ s1 += bnsum[k*NPAD_ + t]; s2 += bnss[k*NPAD_ + t]; }
    const float invN = 1.f/(float)(B_*HW_);
    float mean = s1*invN;
    float var  = s2*invN - mean*mean;
    float sc   = gamma[t] / sqrtf(var + 1e-5f);
    ss[t] = make_float2(sc, beta[t] - mean*sc);
  }
  __syncthreads();

  int prr = t & 15, og = t >> 4;
#pragma unroll
  for (int oi = 0; oi < 5; ++oi){
    int o = og + oi*16;
    if (o < OUT_){
      size_t base = ((size_t)(b*OUT_ + o))*HW_ + p0 + prr*8;
      uint4 raw = *(const uint4*)(yb + base);
      float f[8];
      f[0]=bf2f(raw.x); f[1]=bf2f(raw.x>>16);
      f[2]=bf2f(raw.y); f[3]=bf2f(raw.y>>16);
      f[4]=bf2f(raw.z); f[5]=bf2f(raw.z>>16);
      f[6]=bf2f(raw.w); f[7]=bf2f(raw.w>>16);
      float2 sv = ss[o];
#pragma unroll
      for (int k=0;k<8;++k) f[k] = f[k]*sv.x + sv.y;
      f4 w0 = {f[0],f[1],f[2],f[3]};
      f4 w1 = {f[4],f[5],f[6],f[7]};
      __builtin_nontemporal_store(w0, (f4*)(out_logits + base));
      __builtin_nontemporal_store(w1, (f4*)(out_logits + base + 4));
      uint4 st;
      st.x = pk(f[0],f[1]); st.y = pk(f[2],f[3]);
      st.z = pk(f[4],f[5]); st.w = pk(f[6],f[7]);
      *(uint4*)(lt + o*136 + prr*8) = st;
    }
  }
  __syncthreads();

  /* exp phase: 2 threads per px (o-split 33/32), exp written back as bf16 */
  int px = t & 127, hf = t >> 7;
  {
    int obeg = hf ? 33 : 0, oend = hf ? OUT_ : 33;
    float ssum = 0.f;
    for (int o = obeg; o < oend; ++o){
      float ev = __expf(bf2f(lt[o*136 + px]));
      lt[o*136 + px] = (uint16_t)f2bf(ev);
      ssum += ev;
    }
    sden[hf*128 + px] = ssum;
  }
  __syncthreads();
  {
    float inv = 1.f/(sden[px] + sden[128 + px]);
    int P = p0 + px;
    int hh = P >> 6, wd = P & 63;
    float* pb = out_prob + ((size_t)b << 18) + (size_t)(hh*8)*512 + (size_t)wd*8;
#pragma unroll
    for (int r1i = 0; r1i < 4; ++r1i){
      int r1 = hf*4 + r1i;
      f4 q0, q1;
      q0[0] = bf2f(lt[(r1*8+0)*136+px])*inv;
      q0[1] = bf2f(lt[(r1*8+1)*136+px])*inv;
      q0[2] = bf2f(lt[(r1*8+2)*136+px])*inv;
      q0[3] = bf2f(lt[(r1*8+3)*136+px])*inv;
      q1[0] = bf2f(lt[(r1*8+4)*136+px])*inv;
      q1[1] = bf2f(lt[(r1*8+5)*136+px])*inv;
      q1[2] = bf2f(lt[(r1*8+6)*136+px])*inv;
      q1[3] = bf2f(lt[(r1*8+7)*136+px])*inv;
      __builtin_nontemporal_store(q0, (f4*)(pb + (size_t)r1*512));
      __builtin_nontemporal_store(q1, (f4*)(pb + (size_t)r1*512 + 4));
    }
  }

  /* lb_loss from published expert selections */
  if (bid == 0){
    if (t < 64) ish[t] = esel[t];
    __syncthreads();
    if (t == 0){
      int cnt[4] = {0,0,0,0};
      for (int b2 = 0; b2 < 64; ++b2) cnt[ish[b2]]++;
      double u[4], S = 0.0;
      for (int e2 = 0; e2 < 4; ++e2){ u[e2] = cnt[e2]/64.0 + 1e-6; S += u[e2]; }
      double lbv = 0.0;
      for (int e2 = 0; e2 < 4; ++e2){ double uu = u[e2]/S; lbv += uu*(log(uu) - log(0.25)); }
      *out_lb = (float)lbv;
    }
  }
}

extern "C" void kernel_launch(void* const* d_in, const int* in_sizes, int n_in,
                              void* d_out, int out_size, void* d_ws, size_t ws_size,
                              hipStream_t stream){
  const float* x         = (const float*)d_in[0];
  const float* w_experts = (const float*)d_in[1];
  const float* b_experts = (const float*)d_in[2];
  const float* w_gate    = (const float*)d_in[3];
  const float* b_gate    = (const float*)d_in[4];
  const float* gamma     = (const float*)d_in[5];
  const float* beta      = (const float*)d_in[6];

  float* out = (float*)d_out;
  char*  ws  = (char*)d_ws;
  float*     pp     = (float*)(ws + PP_OFF);
  int*       eselw  = (int*)(ws + ESEL_OFF);
  float*     bnsum  = (float*)(ws + BNS_OFF);
  float*     bnss   = (float*)(ws + BNSS_OFF);
  uint16_t*  Wt     = (uint16_t*)(ws + WT_OFF);
  uint16_t*  ybm    = (uint16_t*)(ws + YB_OFF);
  /* xb (128 MiB, bf16 tiled) lives in d_out: fully consumed by k_gemm
     before k_final overwrites d_out with logits/prob. */
  uint16_t*  xbm    = (uint16_t*)d_out;

  float* logits = out;
  float* prob   = out + LOGITS_SZ;
  float* lbp    = out + LOGITS_SZ + PROB_SZ;

  k_prep <<<8512, 256, 0, stream>>>(x, w_experts, xbm, Wt, pp, bnsum);
  k_gemm <<<2048, 256, 0, stream>>>(xbm, Wt, pp, w_gate, b_gate, b_experts,
                                    ybm, bnsum, bnss, eselw);
  k_final<<<2048, 256, 0, stream>>>(ybm, bnsum, bnss, gamma, beta, eselw,
                                    logits, prob, lbp);
}